// Round 2
// baseline (507.024 us; speedup 1.0000x reference)
//
#include <hip/hip_runtime.h>

// ---------------------------------------------------------------------------
// TrendAttentionLayer: q/k/v proj -> attn_i = Q_i K^T (i=1..3, Q strided) ->
// softmax over s -> colsum over l -> out = v * mean(colsum)/3.
// Precision: all matmuls via bf16-split (hi+lo) MFMA => ~f32 accuracy.
// Structure: pass1 writes attn (500MB, write-bound), pass2 reads it back for
// softmax+colsum (read-bound), small epilogue kernels. No atomics.
// ---------------------------------------------------------------------------

typedef short s16x8 __attribute__((ext_vector_type(8)));
typedef float f32x4 __attribute__((ext_vector_type(4)));

#define MFMA16(a, b, c) __builtin_amdgcn_mfma_f32_16x16x32_bf16((a), (b), (c), 0, 0, 0)

__device__ __forceinline__ unsigned short f32_to_bf16(float f) {
  unsigned u = __builtin_bit_cast(unsigned, f);
  unsigned r = u + 0x7fffu + ((u >> 16) & 1u);  // round-to-nearest-even
  return (unsigned short)(r >> 16);
}

// Load 8 contiguous f32, split each into hi/lo bf16 halves.
__device__ __forceinline__ void split8(const float* __restrict__ p, s16x8& hi, s16x8& lo) {
  float4 a = *(const float4*)p;
  float4 b = *(const float4*)(p + 4);
  float x[8] = {a.x, a.y, a.z, a.w, b.x, b.y, b.z, b.w};
#pragma unroll
  for (int j = 0; j < 8; ++j) {
    unsigned short h = f32_to_bf16(x[j]);
    float hf = __builtin_bit_cast(float, (unsigned)h << 16);
    unsigned short l = f32_to_bf16(x[j] - hf);
    hi[j] = (short)h;
    lo[j] = (short)l;
  }
}

// ---------------------------------------------------------------------------
// Kernel 0: 512x512 transpose (W[k][n] -> Wt[n][k]) so proj B-frags are
// contiguous in k.
// ---------------------------------------------------------------------------
__global__ __launch_bounds__(256) void transpose512(const float* __restrict__ W,
                                                    float* __restrict__ Wt) {
  __shared__ float t[32][33];
  int bx = blockIdx.x * 32, by = blockIdx.y * 32;
  int x = threadIdx.x, y = threadIdx.y;  // block (32,8)
#pragma unroll
  for (int j = 0; j < 32; j += 8) t[y + j][x] = W[(size_t)(by + y + j) * 512 + bx + x];
  __syncthreads();
#pragma unroll
  for (int j = 0; j < 32; j += 8) Wt[(size_t)(bx + y + j) * 512 + by + x] = t[x][y + j];
}

// ---------------------------------------------------------------------------
// Kernel 1: projection GEMM  Y = X(Mx512) @ W(512x512) + b, via Wt.
// 128x128 block tile, 4 waves (2x2), 64x64 per wave, bf16-split MFMA.
// ---------------------------------------------------------------------------
__global__ __launch_bounds__(256) void proj_gemm(const float* __restrict__ X,
                                                 const float* __restrict__ Wt,
                                                 const float* __restrict__ bias,
                                                 float* __restrict__ Y) {
  const int K = 512, N = 512;
  int tid = threadIdx.x;
  int wid = tid >> 6, lane = tid & 63;
  int wr = wid >> 1, wc = wid & 1;
  int m0 = blockIdx.y * 128 + wr * 64;
  int n0 = blockIdx.x * 128 + wc * 64;
  int lr = lane & 15;
  int lk = (lane >> 4) * 8;

  f32x4 zero = {0.f, 0.f, 0.f, 0.f};
  f32x4 acc[4][4];
#pragma unroll
  for (int m = 0; m < 4; ++m)
#pragma unroll
    for (int n = 0; n < 4; ++n) acc[m][n] = zero;

  for (int k0 = 0; k0 < K; k0 += 32) {
    s16x8 ah[4], al[4], bh[4], bl[4];
#pragma unroll
    for (int m = 0; m < 4; ++m)
      split8(X + (size_t)(m0 + m * 16 + lr) * K + k0 + lk, ah[m], al[m]);
#pragma unroll
    for (int n = 0; n < 4; ++n)
      split8(Wt + (size_t)(n0 + n * 16 + lr) * K + k0 + lk, bh[n], bl[n]);
#pragma unroll
    for (int m = 0; m < 4; ++m)
#pragma unroll
      for (int n = 0; n < 4; ++n) {
        acc[m][n] = MFMA16(ah[m], bh[n], acc[m][n]);
        acc[m][n] = MFMA16(ah[m], bl[n], acc[m][n]);
        acc[m][n] = MFMA16(al[m], bh[n], acc[m][n]);
      }
  }
  // D layout: col = lane&15, row = (lane>>4)*4 + r   [m89-verified]
  int cn = lane & 15, cr0 = (lane >> 4) * 4;
#pragma unroll
  for (int n = 0; n < 4; ++n) {
    float bv = bias[n0 + n * 16 + cn];
#pragma unroll
    for (int m = 0; m < 4; ++m)
#pragma unroll
      for (int r = 0; r < 4; ++r) {
        int row = m0 + m * 16 + cr0 + r;
        Y[(size_t)row * N + n0 + n * 16 + cn] = acc[m][n][r] + bv;
      }
  }
}

// ---------------------------------------------------------------------------
// Kernel 2: attn_i[b,h,l,s] = sum_e q[b, l*stride, h, e] * k[b, s, h, e]
// 128(l) x 128(s) per block, 4 waves 2x2, K-depth 64 (2 chunks of 32).
// Fragments loaded directly from global (L2-served), bf16-split MFMA.
// ---------------------------------------------------------------------------
__global__ __launch_bounds__(256) void attn_qk(const float* __restrict__ q,
                                               const float* __restrict__ k,
                                               float* __restrict__ a1,
                                               float* __restrict__ a2,
                                               float* __restrict__ a3) {
  int z = blockIdx.z;            // (b,h,i) in [0,48)
  int b = z / 24, h = (z / 3) % 8, i = z % 3;
  int stride = i + 1;
  int Li = (i == 0) ? 2048 : (i == 1) ? 1024 : 683;
  int ltile = blockIdx.y;
  if (ltile * 128 >= Li) return;
  float* Aout = ((i == 0) ? a1 : (i == 1) ? a2 : a3) + (size_t)(b * 8 + h) * Li * 2048;

  int tid = threadIdx.x, wid = tid >> 6, lane = tid & 63;
  int wr = wid >> 1, wc = wid & 1;
  int lbase = ltile * 128 + wr * 64;
  int sbase = blockIdx.x * 128 + wc * 64;
  int lr = lane & 15, lk = (lane >> 4) * 8;

  f32x4 zero = {0.f, 0.f, 0.f, 0.f};
  f32x4 acc[4][4];
#pragma unroll
  for (int m = 0; m < 4; ++m)
#pragma unroll
    for (int n = 0; n < 4; ++n) acc[m][n] = zero;

#pragma unroll
  for (int kc = 0; kc < 2; ++kc) {
    s16x8 qh[4], ql[4], kh[4], kl[4];
#pragma unroll
    for (int m = 0; m < 4; ++m) {
      int l = lbase + m * 16 + lr;
      if (l > Li - 1) l = Li - 1;  // clamp (duplicate row; write is masked)
      split8(q + ((size_t)(b * 2048 + l * stride) * 8 + h) * 64 + kc * 32 + lk, qh[m], ql[m]);
    }
#pragma unroll
    for (int n = 0; n < 4; ++n) {
      int s = sbase + n * 16 + lr;
      split8(k + ((size_t)(b * 2048 + s) * 8 + h) * 64 + kc * 32 + lk, kh[n], kl[n]);
    }
#pragma unroll
    for (int m = 0; m < 4; ++m)
#pragma unroll
      for (int n = 0; n < 4; ++n) {
        acc[m][n] = MFMA16(qh[m], kh[n], acc[m][n]);
        acc[m][n] = MFMA16(qh[m], kl[n], acc[m][n]);
        acc[m][n] = MFMA16(ql[m], kh[n], acc[m][n]);
      }
  }

  int cn = lane & 15, cr0 = (lane >> 4) * 4;
#pragma unroll
  for (int m = 0; m < 4; ++m)
#pragma unroll
    for (int r = 0; r < 4; ++r) {
      int row = lbase + m * 16 + cr0 + r;
      if (row < Li) {
        float* rowp = Aout + (size_t)row * 2048 + sbase;
#pragma unroll
        for (int n = 0; n < 4; ++n) rowp[n * 16 + cn] = acc[m][n][r];
      }
    }
}

// ---------------------------------------------------------------------------
// Kernel 3: per-row softmax stats + column-sum partials.
// One wave per row (2048 f32 -> 32 VGPRs, single HBM read); colsum kept in
// registers (lane<->position mapping row-invariant); block-reduce via LDS.
// Block handles a 64-row chunk of one (b,h,i).
// ---------------------------------------------------------------------------
__global__ __launch_bounds__(256) void softmax_colsum(const float* __restrict__ a1,
                                                      const float* __restrict__ a2,
                                                      const float* __restrict__ a3,
                                                      float* __restrict__ partials) {
  int z = blockIdx.z;
  int b = z / 24, h = (z / 3) % 8, i = z % 3;
  int Li = (i == 0) ? 2048 : (i == 1) ? 1024 : 683;
  int nch = (Li + 63) >> 6;
  int chunk = blockIdx.y;
  if (chunk >= nch) return;
  const float* Ai = (i == 0) ? a1 : (i == 1) ? a2 : a3;
  const float* A = Ai + (size_t)(b * 8 + h) * Li * 2048;
  int cum = (i == 0) ? 0 : (i == 1) ? 32 : 48;

  int tid = threadIdx.x, wid = tid >> 6, lane = tid & 63;

  float csum[32];
#pragma unroll
  for (int j = 0; j < 32; ++j) csum[j] = 0.f;

  for (int t = 0; t < 16; ++t) {
    int row = chunk * 64 + t * 4 + wid;
    if (row < Li) {
      const float4* rp = (const float4*)(A + (size_t)row * 2048);
      float4 v[8];
      float m = -3.4e38f;
#pragma unroll
      for (int j = 0; j < 8; ++j) {
        v[j] = rp[j * 64 + lane];
        m = fmaxf(m, fmaxf(fmaxf(v[j].x, v[j].y), fmaxf(v[j].z, v[j].w)));
      }
#pragma unroll
      for (int o = 1; o < 64; o <<= 1) m = fmaxf(m, __shfl_xor(m, o));
      float se = 0.f;
#pragma unroll
      for (int j = 0; j < 8; ++j) {
        v[j].x = __expf(v[j].x - m);
        v[j].y = __expf(v[j].y - m);
        v[j].z = __expf(v[j].z - m);
        v[j].w = __expf(v[j].w - m);
        se += (v[j].x + v[j].y) + (v[j].z + v[j].w);
      }
#pragma unroll
      for (int o = 1; o < 64; o <<= 1) se += __shfl_xor(se, o);
      float inv = 1.f / se;
#pragma unroll
      for (int j = 0; j < 8; ++j) {
        csum[j * 4 + 0] += v[j].x * inv;
        csum[j * 4 + 1] += v[j].y * inv;
        csum[j * 4 + 2] += v[j].z * inv;
        csum[j * 4 + 3] += v[j].w * inv;
      }
    }
  }

  __shared__ float part[4][2048];
#pragma unroll
  for (int j = 0; j < 8; ++j) {
    float4 c4 = {csum[j * 4 + 0], csum[j * 4 + 1], csum[j * 4 + 2], csum[j * 4 + 3]};
    ((float4*)&part[wid][0])[j * 64 + lane] = c4;
  }
  __syncthreads();
  size_t base = ((size_t)(b * 8 + h) * 59 + cum + chunk) * 2048;
#pragma unroll
  for (int p = 0; p < 8; ++p) {
    int pos = p * 256 + tid;
    partials[base + pos] = part[0][pos] + part[1][pos] + part[2][pos] + part[3][pos];
  }
}

// ---------------------------------------------------------------------------
// Kernel 4: csum_total[b,h,s] = sum over 59 partial chunks (all i, all chunks)
// ---------------------------------------------------------------------------
__global__ __launch_bounds__(256) void reduce_partials(const float* __restrict__ partials,
                                                       float* __restrict__ csum) {
  int s = blockIdx.x * 256 + threadIdx.x;  // 0..2047
  int bh = blockIdx.y;                     // 0..15
  float acc = 0.f;
  for (int j = 0; j < 59; ++j) acc += partials[((size_t)(bh * 59 + j)) * 2048 + s];
  csum[(size_t)bh * 2048 + s] = acc;
}

// ---------------------------------------------------------------------------
// Kernel 5: out[b,s,h*64+e] = v[b,s,h,e] * csum_total[b,h,s] / 3
// ---------------------------------------------------------------------------
__global__ __launch_bounds__(256) void final_out(const float* __restrict__ v,
                                                 const float* __restrict__ csum,
                                                 float* __restrict__ out) {
  int idx = blockIdx.x * 256 + threadIdx.x;  // float4 index, 524288 total
  int h = (idx >> 4) & 7;
  int s = (idx >> 7) & 2047;
  int b = idx >> 18;
  float4 vv = ((const float4*)v)[idx];
  float c = csum[(size_t)(b * 8 + h) * 2048 + s] * (1.f / 3.f);
  float4 o = {vv.x * c, vv.y * c, vv.z * c, vv.w * c};
  ((float4*)out)[idx] = o;
}

// ---------------------------------------------------------------------------
extern "C" void kernel_launch(void* const* d_in, const int* in_sizes, int n_in,
                              void* d_out, int out_size, void* d_ws, size_t ws_size,
                              hipStream_t stream) {
  const float* queries = (const float*)d_in[0];
  const float* keys    = (const float*)d_in[1];
  const float* values  = (const float*)d_in[2];
  const float* Wq = (const float*)d_in[3];
  const float* bq = (const float*)d_in[4];
  const float* Wk = (const float*)d_in[5];
  const float* bk = (const float*)d_in[6];
  const float* Wv = (const float*)d_in[7];
  const float* bv = (const float*)d_in[8];

  float* out = (float*)d_out;                 // (2,2048,512)      = 2097152
  float* a1 = out + 2097152;                  // (2,8,2048,2048)   = 67108864
  float* a2 = a1 + 67108864;                  // (2,8,1024,2048)   = 33554432
  float* a3 = a2 + 33554432;                  // (2,8, 683,2048)   = 22380544

  float* ws = (float*)d_ws;
  float* q  = ws;                  // 2097152
  float* k  = q + 2097152;         // 2097152
  float* v  = k + 2097152;         // 2097152
  float* Wt = v + 2097152;         // 3 * 262144
  float* partials = Wt + 3 * 262144;  // 944 * 2048 = 1933312
  float* csum = partials + 944 * 2048;  // 32768

  dim3 tb(32, 8);
  transpose512<<<dim3(16, 16), tb, 0, stream>>>(Wq, Wt + 0 * 262144);
  transpose512<<<dim3(16, 16), tb, 0, stream>>>(Wk, Wt + 1 * 262144);
  transpose512<<<dim3(16, 16), tb, 0, stream>>>(Wv, Wt + 2 * 262144);

  proj_gemm<<<dim3(4, 32), 256, 0, stream>>>(queries, Wt + 0 * 262144, bq, q);
  proj_gemm<<<dim3(4, 32), 256, 0, stream>>>(keys,    Wt + 1 * 262144, bk, k);
  proj_gemm<<<dim3(4, 32), 256, 0, stream>>>(values,  Wt + 2 * 262144, bv, v);

  attn_qk<<<dim3(16, 16, 48), 256, 0, stream>>>(q, k, a1, a2, a3);

  softmax_colsum<<<dim3(1, 32, 48), 256, 0, stream>>>(a1, a2, a3, partials);

  reduce_partials<<<dim3(8, 16), 256, 0, stream>>>(partials, csum);

  final_out<<<dim3(2048), 256, 0, stream>>>(v, csum, out);
}

// Round 3
// 361.184 us; speedup vs baseline: 1.4038x; 1.4038x over previous
//
#include <hip/hip_runtime.h>

// ---------------------------------------------------------------------------
// TrendAttentionLayer, round 2.
// Key algebra: attn2[l,s] = attn1[2l,s], attn3[l,s] = attn1[3l,s] (strided Q,
// same K). So: compute only attn1 tiles, fan out rows to a2/a3. And since only
// colsum1+colsum2+colsum3 feeds the output, the softmax pass reads ONLY a1 and
// weights each row by w = 1 + [l%2==0] + [l%3==0].
// Precision: bf16-split (hi+lo) MFMA, split precomputed in proj epilogue.
// ---------------------------------------------------------------------------

typedef short s16x8 __attribute__((ext_vector_type(8)));
typedef float f32x4 __attribute__((ext_vector_type(4)));
typedef unsigned short u16;

#define MFMA16(a, b, c) __builtin_amdgcn_mfma_f32_16x16x32_bf16((a), (b), (c), 0, 0, 0)

__device__ __forceinline__ u16 f32_to_bf16(float f) {
  unsigned u = __builtin_bit_cast(unsigned, f);
  unsigned r = u + 0x7fffu + ((u >> 16) & 1u);  // round-to-nearest-even
  return (u16)(r >> 16);
}

// ---------------------------------------------------------------------------
// Kernel 0: 512x512 transpose (W[k][n] -> Wt[n][k]).
// ---------------------------------------------------------------------------
__global__ __launch_bounds__(256) void transpose512(const float* __restrict__ W,
                                                    float* __restrict__ Wt) {
  __shared__ float t[32][33];
  int bx = blockIdx.x * 32, by = blockIdx.y * 32;
  int x = threadIdx.x, y = threadIdx.y;  // block (32,8)
#pragma unroll
  for (int j = 0; j < 32; j += 8) t[y + j][x] = W[(size_t)(by + y + j) * 512 + bx + x];
  __syncthreads();
#pragma unroll
  for (int j = 0; j < 32; j += 8) Wt[(size_t)(bx + y + j) * 512 + by + x] = t[x][y + j];
}

// ---------------------------------------------------------------------------
// Kernel 1: projection GEMM Y = X(4096x512) @ W(512x512) + b via Wt.
// mode 0: write f32 (for v). mode 1: write bf16 hi/lo split (for q, k) so the
// attention kernel loads MFMA-ready fragments with zero per-element VALU.
// 128x128 tile, 4 waves 2x2, 64x64/wave, bf16-split MFMA (hh+hl+lh).
// ---------------------------------------------------------------------------
__global__ __launch_bounds__(256) void proj_gemm(const float* __restrict__ X,
                                                 const float* __restrict__ Wt,
                                                 const float* __restrict__ bias,
                                                 float* __restrict__ Yf32,
                                                 u16* __restrict__ Yhi,
                                                 u16* __restrict__ Ylo,
                                                 int bf16mode) {
  const int K = 512, N = 512;
  int tid = threadIdx.x;
  int wid = tid >> 6, lane = tid & 63;
  int wr = wid >> 1, wc = wid & 1;
  int m0 = blockIdx.y * 128 + wr * 64;
  int n0 = blockIdx.x * 128 + wc * 64;
  int lr = lane & 15;
  int lk = (lane >> 4) * 8;

  f32x4 zero = {0.f, 0.f, 0.f, 0.f};
  f32x4 acc[4][4];
#pragma unroll
  for (int m = 0; m < 4; ++m)
#pragma unroll
    for (int n = 0; n < 4; ++n) acc[m][n] = zero;

  for (int k0 = 0; k0 < K; k0 += 32) {
    s16x8 ah[4], al[4], bh[4], bl[4];
#pragma unroll
    for (int m = 0; m < 4; ++m) {
      const float* p = X + (size_t)(m0 + m * 16 + lr) * K + k0 + lk;
      float4 a = *(const float4*)p;
      float4 b = *(const float4*)(p + 4);
      float x[8] = {a.x, a.y, a.z, a.w, b.x, b.y, b.z, b.w};
#pragma unroll
      for (int j = 0; j < 8; ++j) {
        u16 hh = f32_to_bf16(x[j]);
        ah[m][j] = (short)hh;
        al[m][j] = (short)f32_to_bf16(x[j] - __builtin_bit_cast(float, (unsigned)hh << 16));
      }
    }
#pragma unroll
    for (int n = 0; n < 4; ++n) {
      const float* p = Wt + (size_t)(n0 + n * 16 + lr) * K + k0 + lk;
      float4 a = *(const float4*)p;
      float4 b = *(const float4*)(p + 4);
      float x[8] = {a.x, a.y, a.z, a.w, b.x, b.y, b.z, b.w};
#pragma unroll
      for (int j = 0; j < 8; ++j) {
        u16 hh = f32_to_bf16(x[j]);
        bh[n][j] = (short)hh;
        bl[n][j] = (short)f32_to_bf16(x[j] - __builtin_bit_cast(float, (unsigned)hh << 16));
      }
    }
#pragma unroll
    for (int m = 0; m < 4; ++m)
#pragma unroll
      for (int n = 0; n < 4; ++n) {
        acc[m][n] = MFMA16(ah[m], bh[n], acc[m][n]);
        acc[m][n] = MFMA16(ah[m], bl[n], acc[m][n]);
        acc[m][n] = MFMA16(al[m], bh[n], acc[m][n]);
      }
  }
  // D layout: col = lane&15, row = (lane>>4)*4 + r
  int cn = lane & 15, cr0 = (lane >> 4) * 4;
#pragma unroll
  for (int n = 0; n < 4; ++n) {
    float bv = bias[n0 + n * 16 + cn];
#pragma unroll
    for (int m = 0; m < 4; ++m)
#pragma unroll
      for (int r = 0; r < 4; ++r) {
        int row = m0 + m * 16 + cr0 + r;
        size_t idx = (size_t)row * N + n0 + n * 16 + cn;
        float y = acc[m][n][r] + bv;
        if (!bf16mode) {
          Yf32[idx] = y;
        } else {
          u16 hh = f32_to_bf16(y);
          Yhi[idx] = hh;
          Ylo[idx] = f32_to_bf16(y - __builtin_bit_cast(float, (unsigned)hh << 16));
        }
      }
  }
}

// ---------------------------------------------------------------------------
// Kernel 2: attn1[bh,l,s] = sum_e q[b,l,h,e]*k[b,s,h,e]; rows fanned out to
// a2 (l%2==0 -> l/2) and a3 (l%3==0 -> l/3). 128x128 tile, 4 waves 2x2,
// K-depth 64 (2 chunks), fragments are precomputed bf16 hi/lo (pure 16B loads).
// a2/a3 stored non-temporally (never re-read) to keep L3 warm for a1.
// ---------------------------------------------------------------------------
__global__ __launch_bounds__(256) void attn_qk(const u16* __restrict__ qh,
                                               const u16* __restrict__ ql,
                                               const u16* __restrict__ kh,
                                               const u16* __restrict__ kl,
                                               float* __restrict__ a1,
                                               float* __restrict__ a2,
                                               float* __restrict__ a3) {
  int bh = blockIdx.z;  // b*8+h, 0..15
  int b = bh >> 3, h = bh & 7;
  int tid = threadIdx.x, wid = tid >> 6, lane = tid & 63;
  int wr = wid >> 1, wc = wid & 1;
  int lbase = blockIdx.y * 128 + wr * 64;
  int sbase = blockIdx.x * 128 + wc * 64;
  int lr = lane & 15, lk = (lane >> 4) * 8;

  f32x4 zero = {0.f, 0.f, 0.f, 0.f};
  f32x4 acc[4][4];
#pragma unroll
  for (int m = 0; m < 4; ++m)
#pragma unroll
    for (int n = 0; n < 4; ++n) acc[m][n] = zero;

#pragma unroll
  for (int kc = 0; kc < 2; ++kc) {
    s16x8 qhf[4], qlf[4], khf[4], klf[4];
#pragma unroll
    for (int m = 0; m < 4; ++m) {
      size_t off = ((size_t)(b * 2048 + lbase + m * 16 + lr) * 8 + h) * 64 + kc * 32 + lk;
      qhf[m] = *(const s16x8*)(qh + off);
      qlf[m] = *(const s16x8*)(ql + off);
    }
#pragma unroll
    for (int n = 0; n < 4; ++n) {
      size_t off = ((size_t)(b * 2048 + sbase + n * 16 + lr) * 8 + h) * 64 + kc * 32 + lk;
      khf[n] = *(const s16x8*)(kh + off);
      klf[n] = *(const s16x8*)(kl + off);
    }
#pragma unroll
    for (int m = 0; m < 4; ++m)
#pragma unroll
      for (int n = 0; n < 4; ++n) {
        acc[m][n] = MFMA16(qhf[m], khf[n], acc[m][n]);
        acc[m][n] = MFMA16(qhf[m], klf[n], acc[m][n]);
        acc[m][n] = MFMA16(qlf[m], khf[n], acc[m][n]);
      }
  }

  int cn = lane & 15, cr0 = (lane >> 4) * 4;
  float* A1 = a1 + (size_t)bh * 2048 * 2048;
  float* A2 = a2 + (size_t)bh * 1024 * 2048;
  float* A3 = a3 + (size_t)bh * 683 * 2048;
#pragma unroll
  for (int m = 0; m < 4; ++m)
#pragma unroll
    for (int r = 0; r < 4; ++r) {
      int row = lbase + m * 16 + cr0 + r;
      float* p1 = A1 + (size_t)row * 2048 + sbase;
#pragma unroll
      for (int n = 0; n < 4; ++n) p1[n * 16 + cn] = acc[m][n][r];
      if ((row & 1) == 0) {
        float* p2 = A2 + (size_t)(row >> 1) * 2048 + sbase;
#pragma unroll
        for (int n = 0; n < 4; ++n) __builtin_nontemporal_store(acc[m][n][r], p2 + n * 16 + cn);
      }
      if (row % 3 == 0) {
        float* p3 = A3 + (size_t)(row / 3) * 2048 + sbase;
#pragma unroll
        for (int n = 0; n < 4; ++n) __builtin_nontemporal_store(acc[m][n][r], p3 + n * 16 + cn);
      }
    }
}

// ---------------------------------------------------------------------------
// Kernel 3: weighted softmax colsum over a1 ONLY.
// One wave per row (2048 f32 in 32 VGPRs, single read); csum in registers,
// row weight w = 1 + [l%2==0] + [l%3==0]; block = 32 rows, LDS reduce.
// ---------------------------------------------------------------------------
__global__ __launch_bounds__(256) void softmax_colsum(const float* __restrict__ a1,
                                                      float* __restrict__ partials) {
  int bh = blockIdx.y;     // 0..15
  int chunk = blockIdx.x;  // 0..63, 32 rows each
  const float* A = a1 + (size_t)bh * 2048 * 2048;
  int tid = threadIdx.x, wid = tid >> 6, lane = tid & 63;

  float csum[32];
#pragma unroll
  for (int j = 0; j < 32; ++j) csum[j] = 0.f;

  for (int t = 0; t < 8; ++t) {
    int row = chunk * 32 + t * 4 + wid;
    const float4* rp = (const float4*)(A + (size_t)row * 2048);
    float4 v[8];
    float m = -3.4e38f;
#pragma unroll
    for (int j = 0; j < 8; ++j) {
      v[j] = rp[j * 64 + lane];
      m = fmaxf(m, fmaxf(fmaxf(v[j].x, v[j].y), fmaxf(v[j].z, v[j].w)));
    }
#pragma unroll
    for (int o = 1; o < 64; o <<= 1) m = fmaxf(m, __shfl_xor(m, o));
    float se = 0.f;
#pragma unroll
    for (int j = 0; j < 8; ++j) {
      v[j].x = __expf(v[j].x - m);
      v[j].y = __expf(v[j].y - m);
      v[j].z = __expf(v[j].z - m);
      v[j].w = __expf(v[j].w - m);
      se += (v[j].x + v[j].y) + (v[j].z + v[j].w);
    }
#pragma unroll
    for (int o = 1; o < 64; o <<= 1) se += __shfl_xor(se, o);
    float w = 1.f + ((row & 1) == 0 ? 1.f : 0.f) + (row % 3 == 0 ? 1.f : 0.f);
    float inv = w / se;
#pragma unroll
    for (int j = 0; j < 8; ++j) {
      csum[j * 4 + 0] += v[j].x * inv;
      csum[j * 4 + 1] += v[j].y * inv;
      csum[j * 4 + 2] += v[j].z * inv;
      csum[j * 4 + 3] += v[j].w * inv;
    }
  }

  __shared__ float part[4][2048];
#pragma unroll
  for (int j = 0; j < 8; ++j) {
    float4 c4 = {csum[j * 4 + 0], csum[j * 4 + 1], csum[j * 4 + 2], csum[j * 4 + 3]};
    ((float4*)&part[wid][0])[j * 64 + lane] = c4;
  }
  __syncthreads();
  size_t base = ((size_t)bh * 64 + chunk) * 2048;
#pragma unroll
  for (int p = 0; p < 8; ++p) {
    int pos = p * 256 + tid;
    partials[base + pos] = part[0][pos] + part[1][pos] + part[2][pos] + part[3][pos];
  }
}

// ---------------------------------------------------------------------------
// Kernel 4: csum_total[bh,s] = sum over 64 chunk partials.
// ---------------------------------------------------------------------------
__global__ __launch_bounds__(256) void reduce_partials(const float* __restrict__ partials,
                                                       float* __restrict__ csum) {
  int s = blockIdx.x * 256 + threadIdx.x;  // 0..2047
  int bh = blockIdx.y;                     // 0..15
  float acc = 0.f;
  for (int j = 0; j < 64; ++j) acc += partials[((size_t)(bh * 64 + j)) * 2048 + s];
  csum[(size_t)bh * 2048 + s] = acc;
}

// ---------------------------------------------------------------------------
// Kernel 5: out[b,s,h*64+e] = v[b,s,h,e] * csum_total[b,h,s] / 3
// ---------------------------------------------------------------------------
__global__ __launch_bounds__(256) void final_out(const float* __restrict__ v,
                                                 const float* __restrict__ csum,
                                                 float* __restrict__ out) {
  int idx = blockIdx.x * 256 + threadIdx.x;  // float4 index, 524288 total
  int h = (idx >> 4) & 7;
  int s = (idx >> 7) & 2047;
  int b = idx >> 18;
  float4 vv = ((const float4*)v)[idx];
  float c = csum[(size_t)(b * 8 + h) * 2048 + s] * (1.f / 3.f);
  float4 o = {vv.x * c, vv.y * c, vv.z * c, vv.w * c};
  ((float4*)out)[idx] = o;
}

// ---------------------------------------------------------------------------
extern "C" void kernel_launch(void* const* d_in, const int* in_sizes, int n_in,
                              void* d_out, int out_size, void* d_ws, size_t ws_size,
                              hipStream_t stream) {
  const float* queries = (const float*)d_in[0];
  const float* keys    = (const float*)d_in[1];
  const float* values  = (const float*)d_in[2];
  const float* Wq = (const float*)d_in[3];
  const float* bq = (const float*)d_in[4];
  const float* Wk = (const float*)d_in[5];
  const float* bk = (const float*)d_in[6];
  const float* Wv = (const float*)d_in[7];
  const float* bv = (const float*)d_in[8];

  float* out = (float*)d_out;   // (2,2048,512)    = 2097152
  float* a1 = out + 2097152;    // (2,8,2048,2048) = 67108864
  float* a2 = a1 + 67108864;    // (2,8,1024,2048) = 33554432
  float* a3 = a2 + 33554432;    // (2,8, 683,2048) = 22380544

  float* ws = (float*)d_ws;
  float* v        = ws;                  // 2097152 f32
  float* Wt       = v + 2097152;         // 3 * 262144 f32
  float* partials = Wt + 3 * 262144;     // 16*64*2048 = 2097152 f32
  float* csum     = partials + 2097152;  // 32768 f32
  u16* qh = (u16*)(csum + 32768);        // 2097152 u16 each
  u16* ql = qh + 2097152;
  u16* kh = ql + 2097152;
  u16* kl = kh + 2097152;

  dim3 tb(32, 8);
  transpose512<<<dim3(16, 16), tb, 0, stream>>>(Wq, Wt + 0 * 262144);
  transpose512<<<dim3(16, 16), tb, 0, stream>>>(Wk, Wt + 1 * 262144);
  transpose512<<<dim3(16, 16), tb, 0, stream>>>(Wv, Wt + 2 * 262144);

  proj_gemm<<<dim3(4, 32), 256, 0, stream>>>(queries, Wt + 0 * 262144, bq, nullptr, qh, ql, 1);
  proj_gemm<<<dim3(4, 32), 256, 0, stream>>>(keys,    Wt + 1 * 262144, bk, nullptr, kh, kl, 1);
  proj_gemm<<<dim3(4, 32), 256, 0, stream>>>(values,  Wt + 2 * 262144, bv, v, nullptr, nullptr, 0);

  attn_qk<<<dim3(16, 16, 16), 256, 0, stream>>>(qh, ql, kh, kl, a1, a2, a3);

  softmax_colsum<<<dim3(64, 16), 256, 0, stream>>>(a1, partials);

  reduce_partials<<<dim3(8, 16), 256, 0, stream>>>(partials, csum);

  final_out<<<dim3(2048), 256, 0, stream>>>(v, csum, out);
}

// Round 4
// 281.946 us; speedup vs baseline: 1.7983x; 1.2810x over previous
//
#include <hip/hip_runtime.h>

// ---------------------------------------------------------------------------
// TrendAttentionLayer, round 3.
// R2 algebra kept: only attn1 computed (attn2/attn3 are row-subsets), single
// weighted softmax pass over a1 (w = 1 + [l%2==0] + [l%3==0]).
// R3 structural changes:
//  * q/k (and proj inputs X, W) stored in MFMA fragment-major layout
//    [tile16][kchunk][lane][8] -> every fragment load is a lane-consecutive
//    1KB wave-load (was 1KB-strided 16B/lane = 4x L2 amplification).
//  * f32->bf16 hi/lo split hoisted entirely out of GEMM K-loops (prep kernels
//    + proj epilogue). GEMM loops are pure loads+MFMA.
//  * softmax reads a1 in reverse of write order; a2/a3 use NT stores, so L3
//    preferentially retains the tail of a1 -> L3 hits on the re-read.
// ---------------------------------------------------------------------------

typedef short s16x8 __attribute__((ext_vector_type(8)));
typedef float f32x4 __attribute__((ext_vector_type(4)));
typedef unsigned short u16;

#define MFMA16(a, b, c) __builtin_amdgcn_mfma_f32_16x16x32_bf16((a), (b), (c), 0, 0, 0)

__device__ __forceinline__ u16 f32_to_bf16(float f) {
  unsigned u = __builtin_bit_cast(unsigned, f);
  unsigned r = u + 0x7fffu + ((u >> 16) & 1u);  // RTNE
  return (u16)(r >> 16);
}
__device__ __forceinline__ void split1(float x, u16& h, u16& l) {
  h = f32_to_bf16(x);
  l = f32_to_bf16(x - __builtin_bit_cast(float, (unsigned)h << 16));
}

// ---------------------------------------------------------------------------
// Kernel A: split X (M x 512, f32, row-major) into frag-major hi/lo planes:
// element (row = mt*16+lr, k = kc*32+g*8+j) at [((mt*16+kc)*64 + g*16+lr)*8+j].
// One thread per (mt,kc,lane) handles 8 elements; output stores are 16B
// lane-consecutive (fully coalesced).
// ---------------------------------------------------------------------------
__global__ __launch_bounds__(256) void split_x(const float* __restrict__ X,
                                               u16* __restrict__ Xh,
                                               u16* __restrict__ Xl) {
  int t = blockIdx.x * 256 + threadIdx.x;  // < M*64  (M=4096 -> 262144)
  int lane = t & 63;
  int kc = (t >> 6) & 15;
  int mt = t >> 10;
  int lr = lane & 15, g = lane >> 4;
  const float* p = X + (size_t)(mt * 16 + lr) * 512 + kc * 32 + g * 8;
  float4 a = *(const float4*)p;
  float4 b = *(const float4*)(p + 4);
  float x[8] = {a.x, a.y, a.z, a.w, b.x, b.y, b.z, b.w};
  s16x8 hv, lv;
#pragma unroll
  for (int j = 0; j < 8; ++j) {
    u16 hh, ll;
    split1(x[j], hh, ll);
    hv[j] = (short)hh;
    lv[j] = (short)ll;
  }
  size_t off = (size_t)t * 8;
  *(s16x8*)(Xh + off) = hv;
  *(s16x8*)(Xl + off) = lv;
}

// ---------------------------------------------------------------------------
// Kernel B: W (512x512 f32, [k][n]) -> B-frag-major hi/lo planes of Wt[n][k]:
// element (n = nt*16+lr, k = kc*32+g*8+j) at [((nt*16+kc)*64 + g*16+lr)*8+j].
// ---------------------------------------------------------------------------
__global__ __launch_bounds__(256) void split_w(const float* __restrict__ W,
                                               u16* __restrict__ Wh,
                                               u16* __restrict__ Wl) {
  int t = blockIdx.x * 256 + threadIdx.x;  // < 32768
  int lane = t & 63;
  int kc = (t >> 6) & 15;
  int nt = t >> 10;
  int lr = lane & 15, g = lane >> 4;
  s16x8 hv, lv;
#pragma unroll
  for (int j = 0; j < 8; ++j) {
    float x = W[(size_t)(kc * 32 + g * 8 + j) * 512 + nt * 16 + lr];
    u16 hh, ll;
    split1(x, hh, ll);
    hv[j] = (short)hh;
    lv[j] = (short)ll;
  }
  size_t off = (size_t)t * 8;
  *(s16x8*)(Wh + off) = hv;
  *(s16x8*)(Wl + off) = lv;
}

// ---------------------------------------------------------------------------
// Kernel 1: projection GEMM Y = X(4096x512) @ W(512x512) + b.
// Pure loads+MFMA K-loop (fragments pre-split, frag-major, coalesced).
// mode 0: f32 out (v). mode 1: q/k out in ATTENTION frag-major hi/lo layout
// [bh][lt][kc2][lane][8] over (l, e) so attn loads are coalesced too.
// ---------------------------------------------------------------------------
__global__ __launch_bounds__(256) void proj_gemm(const u16* __restrict__ Xh,
                                                 const u16* __restrict__ Xl,
                                                 const u16* __restrict__ Wh,
                                                 const u16* __restrict__ Wl,
                                                 const float* __restrict__ bias,
                                                 float* __restrict__ Yf32,
                                                 u16* __restrict__ Yhi,
                                                 u16* __restrict__ Ylo,
                                                 int bf16mode) {
  int tid = threadIdx.x;
  int wid = tid >> 6, lane = tid & 63;
  int wr = wid >> 1, wc = wid & 1;
  int mtb = blockIdx.y * 8 + wr * 4;  // 16-row tile index base (A)
  int ntb = blockIdx.x * 8 + wc * 4;  // 16-col tile index base (B)

  f32x4 zero = {0.f, 0.f, 0.f, 0.f};
  f32x4 acc[4][4];
#pragma unroll
  for (int m = 0; m < 4; ++m)
#pragma unroll
    for (int n = 0; n < 4; ++n) acc[m][n] = zero;

  for (int kc = 0; kc < 16; ++kc) {
    s16x8 ah[4], al[4], bh[4], bl[4];
#pragma unroll
    for (int m = 0; m < 4; ++m) {
      size_t off = ((size_t)((mtb + m) * 16 + kc) * 64 + lane) * 8;
      ah[m] = *(const s16x8*)(Xh + off);
      al[m] = *(const s16x8*)(Xl + off);
    }
#pragma unroll
    for (int n = 0; n < 4; ++n) {
      size_t off = ((size_t)((ntb + n) * 16 + kc) * 64 + lane) * 8;
      bh[n] = *(const s16x8*)(Wh + off);
      bl[n] = *(const s16x8*)(Wl + off);
    }
#pragma unroll
    for (int m = 0; m < 4; ++m)
#pragma unroll
      for (int n = 0; n < 4; ++n) {
        acc[m][n] = MFMA16(ah[m], bh[n], acc[m][n]);
        acc[m][n] = MFMA16(ah[m], bl[n], acc[m][n]);
        acc[m][n] = MFMA16(al[m], bh[n], acc[m][n]);
      }
  }
  // D layout: col = lane&15, row = (lane>>4)*4 + r
  int cn = lane & 15, cr0 = (lane >> 4) * 4;
#pragma unroll
  for (int n = 0; n < 4; ++n) {
    int col = (ntb + n) * 16 + cn;
    float bv = bias[col];
#pragma unroll
    for (int m = 0; m < 4; ++m)
#pragma unroll
      for (int r = 0; r < 4; ++r) {
        int row = (mtb + m) * 16 + cr0 + r;
        float y = acc[m][n][r] + bv;
        if (!bf16mode) {
          Yf32[(size_t)row * 512 + col] = y;
        } else {
          int b = row >> 11, l = row & 2047;
          int h = col >> 6, e = col & 63;
          int bh2 = b * 8 + h;
          int lt = l >> 4, lr2 = l & 15;
          int kc2 = e >> 5, g2 = (e >> 3) & 3, j2 = e & 7;
          size_t idx = ((((size_t)bh2 * 128 + lt) * 2 + kc2) * 64 + g2 * 16 + lr2) * 8 + j2;
          u16 hh, ll;
          split1(y, hh, ll);
          Yhi[idx] = hh;
          Ylo[idx] = ll;
        }
      }
  }
}

// ---------------------------------------------------------------------------
// Kernel 2: attn1[bh,l,s] = q.k ; rows fanned out to a2 (l%2==0) / a3 (l%3==0).
// 128x128 tile, 4 waves 2x2. Fragments in frag-major layout: every load is a
// lane-consecutive 1KB wave-load. a2/a3 NT-stored (never re-read).
// ---------------------------------------------------------------------------
__global__ __launch_bounds__(256) void attn_qk(const u16* __restrict__ qh,
                                               const u16* __restrict__ ql,
                                               const u16* __restrict__ kh,
                                               const u16* __restrict__ kl,
                                               float* __restrict__ a1,
                                               float* __restrict__ a2,
                                               float* __restrict__ a3) {
  int bh = blockIdx.z;  // 0..15
  int tid = threadIdx.x, wid = tid >> 6, lane = tid & 63;
  int wr = wid >> 1, wc = wid & 1;
  int ltb = blockIdx.y * 8 + wr * 4;  // q 16-row tile base
  int stb = blockIdx.x * 8 + wc * 4;  // k 16-row tile base

  f32x4 zero = {0.f, 0.f, 0.f, 0.f};
  f32x4 acc[4][4];
#pragma unroll
  for (int m = 0; m < 4; ++m)
#pragma unroll
    for (int n = 0; n < 4; ++n) acc[m][n] = zero;

#pragma unroll
  for (int kc = 0; kc < 2; ++kc) {
    s16x8 qhf[4], qlf[4], khf[4], klf[4];
#pragma unroll
    for (int m = 0; m < 4; ++m) {
      size_t off = ((((size_t)bh * 128 + ltb + m) * 2 + kc) * 64 + lane) * 8;
      qhf[m] = *(const s16x8*)(qh + off);
      qlf[m] = *(const s16x8*)(ql + off);
    }
#pragma unroll
    for (int n = 0; n < 4; ++n) {
      size_t off = ((((size_t)bh * 128 + stb + n) * 2 + kc) * 64 + lane) * 8;
      khf[n] = *(const s16x8*)(kh + off);
      klf[n] = *(const s16x8*)(kl + off);
    }
#pragma unroll
    for (int m = 0; m < 4; ++m)
#pragma unroll
      for (int n = 0; n < 4; ++n) {
        acc[m][n] = MFMA16(qhf[m], khf[n], acc[m][n]);
        acc[m][n] = MFMA16(qhf[m], klf[n], acc[m][n]);
        acc[m][n] = MFMA16(qlf[m], khf[n], acc[m][n]);
      }
  }

  int cn = lane & 15, cr0 = (lane >> 4) * 4;
  int lbase = ltb * 16, sbase = stb * 16;
  float* A1 = a1 + (size_t)bh * 2048 * 2048;
  float* A2 = a2 + (size_t)bh * 1024 * 2048;
  float* A3 = a3 + (size_t)bh * 683 * 2048;
#pragma unroll
  for (int m = 0; m < 4; ++m)
#pragma unroll
    for (int r = 0; r < 4; ++r) {
      int row = lbase + m * 16 + cr0 + r;
      float* p1 = A1 + (size_t)row * 2048 + sbase;
#pragma unroll
      for (int n = 0; n < 4; ++n) p1[n * 16 + cn] = acc[m][n][r];
      if ((row & 1) == 0) {
        float* p2 = A2 + (size_t)(row >> 1) * 2048 + sbase;
#pragma unroll
        for (int n = 0; n < 4; ++n) __builtin_nontemporal_store(acc[m][n][r], p2 + n * 16 + cn);
      }
      if (row % 3 == 0) {
        float* p3 = A3 + (size_t)(row / 3) * 2048 + sbase;
#pragma unroll
        for (int n = 0; n < 4; ++n) __builtin_nontemporal_store(acc[m][n][r], p3 + n * 16 + cn);
      }
    }
}

// ---------------------------------------------------------------------------
// Kernel 3: weighted softmax colsum over a1 only. One wave per row; csum in
// registers; w = 1 + [l%2==0] + [l%3==0]. Processes a1 in REVERSE of attn's
// write order to catch the L3-resident tail.
// ---------------------------------------------------------------------------
__global__ __launch_bounds__(256) void softmax_colsum(const float* __restrict__ a1,
                                                      float* __restrict__ partials) {
  int bh = 15 - blockIdx.y;     // reverse order
  int chunk = 63 - blockIdx.x;  // reverse order
  const float* A = a1 + (size_t)bh * 2048 * 2048;
  int tid = threadIdx.x, wid = tid >> 6, lane = tid & 63;

  float csum[32];
#pragma unroll
  for (int j = 0; j < 32; ++j) csum[j] = 0.f;

  for (int t = 0; t < 8; ++t) {
    int row = chunk * 32 + t * 4 + wid;
    const float4* rp = (const float4*)(A + (size_t)row * 2048);
    float4 v[8];
    float m = -3.4e38f;
#pragma unroll
    for (int j = 0; j < 8; ++j) {
      v[j] = rp[j * 64 + lane];
      m = fmaxf(m, fmaxf(fmaxf(v[j].x, v[j].y), fmaxf(v[j].z, v[j].w)));
    }
#pragma unroll
    for (int o = 1; o < 64; o <<= 1) m = fmaxf(m, __shfl_xor(m, o));
    float se = 0.f;
#pragma unroll
    for (int j = 0; j < 8; ++j) {
      v[j].x = __expf(v[j].x - m);
      v[j].y = __expf(v[j].y - m);
      v[j].z = __expf(v[j].z - m);
      v[j].w = __expf(v[j].w - m);
      se += (v[j].x + v[j].y) + (v[j].z + v[j].w);
    }
#pragma unroll
    for (int o = 1; o < 64; o <<= 1) se += __shfl_xor(se, o);
    float w = 1.f + ((row & 1) == 0 ? 1.f : 0.f) + (row % 3 == 0 ? 1.f : 0.f);
    float inv = w / se;
#pragma unroll
    for (int j = 0; j < 8; ++j) {
      csum[j * 4 + 0] += v[j].x * inv;
      csum[j * 4 + 1] += v[j].y * inv;
      csum[j * 4 + 2] += v[j].z * inv;
      csum[j * 4 + 3] += v[j].w * inv;
    }
  }

  __shared__ float part[4][2048];
#pragma unroll
  for (int j = 0; j < 8; ++j) {
    float4 c4 = {csum[j * 4 + 0], csum[j * 4 + 1], csum[j * 4 + 2], csum[j * 4 + 3]};
    ((float4*)&part[wid][0])[j * 64 + lane] = c4;
  }
  __syncthreads();
  size_t base = ((size_t)bh * 64 + chunk) * 2048;
#pragma unroll
  for (int p = 0; p < 8; ++p) {
    int pos = p * 256 + tid;
    partials[base + pos] = part[0][pos] + part[1][pos] + part[2][pos] + part[3][pos];
  }
}

// ---------------------------------------------------------------------------
// Kernel 4: csum_total[bh,s] = sum over 64 chunk partials.
// ---------------------------------------------------------------------------
__global__ __launch_bounds__(256) void reduce_partials(const float* __restrict__ partials,
                                                       float* __restrict__ csum) {
  int s = blockIdx.x * 256 + threadIdx.x;
  int bh = blockIdx.y;
  float acc = 0.f;
  for (int j = 0; j < 64; ++j) acc += partials[((size_t)(bh * 64 + j)) * 2048 + s];
  csum[(size_t)bh * 2048 + s] = acc;
}

// ---------------------------------------------------------------------------
// Kernel 5: out[b,s,h*64+e] = v[b,s,h,e] * csum_total[b,h,s] / 3
// ---------------------------------------------------------------------------
__global__ __launch_bounds__(256) void final_out(const float* __restrict__ v,
                                                 const float* __restrict__ csum,
                                                 float* __restrict__ out) {
  int idx = blockIdx.x * 256 + threadIdx.x;  // float4 index
  int h = (idx >> 4) & 7;
  int s = (idx >> 7) & 2047;
  int b = idx >> 18;
  float4 vv = ((const float4*)v)[idx];
  float c = csum[(size_t)(b * 8 + h) * 2048 + s] * (1.f / 3.f);
  float4 o = {vv.x * c, vv.y * c, vv.z * c, vv.w * c};
  ((float4*)out)[idx] = o;
}

// ---------------------------------------------------------------------------
extern "C" void kernel_launch(void* const* d_in, const int* in_sizes, int n_in,
                              void* d_out, int out_size, void* d_ws, size_t ws_size,
                              hipStream_t stream) {
  const float* queries = (const float*)d_in[0];
  const float* keys    = (const float*)d_in[1];
  const float* values  = (const float*)d_in[2];
  const float* Wq = (const float*)d_in[3];
  const float* bq = (const float*)d_in[4];
  const float* Wk = (const float*)d_in[5];
  const float* bk = (const float*)d_in[6];
  const float* Wv = (const float*)d_in[7];
  const float* bv = (const float*)d_in[8];

  float* out = (float*)d_out;   // (2,2048,512)    = 2097152
  float* a1 = out + 2097152;    // (2,8,2048,2048) = 67108864
  float* a2 = a1 + 67108864;    // (2,8,1024,2048) = 33554432
  float* a3 = a2 + 33554432;    // (2,8, 683,2048) = 22380544

  float* ws = (float*)d_ws;
  float* v = ws;                         // 2,097,152 f32
  u16* qh = (u16*)(v + 2097152);         // 2,097,152 u16 each
  u16* ql = qh + 2097152;
  u16* kh = ql + 2097152;
  u16* kl = kh + 2097152;
  u16* Wh = kl + 2097152;                // 262,144 u16 each
  u16* Wl = Wh + 262144;
  u16* Xh = Wl + 262144;                 // 2,097,152 u16 each
  u16* Xl = Xh + 2097152;
  float* partials = (float*)Xh;          // alias: X planes dead after projs
  float* csum = (float*)(Xl + 2097152);  // 32,768 f32

  // -- prep + projections (Wh/Wl and Xh/Xl reused serially, stream-ordered) --
  split_w<<<dim3(128), 256, 0, stream>>>(Wq, Wh, Wl);
  split_x<<<dim3(1024), 256, 0, stream>>>(queries, Xh, Xl);
  proj_gemm<<<dim3(4, 32), 256, 0, stream>>>(Xh, Xl, Wh, Wl, bq, nullptr, qh, ql, 1);

  split_w<<<dim3(128), 256, 0, stream>>>(Wk, Wh, Wl);
  split_x<<<dim3(1024), 256, 0, stream>>>(keys, Xh, Xl);
  proj_gemm<<<dim3(4, 32), 256, 0, stream>>>(Xh, Xl, Wh, Wl, bk, nullptr, kh, kl, 1);

  split_w<<<dim3(128), 256, 0, stream>>>(Wv, Wh, Wl);
  split_x<<<dim3(1024), 256, 0, stream>>>(values, Xh, Xl);
  proj_gemm<<<dim3(4, 32), 256, 0, stream>>>(Xh, Xl, Wh, Wl, bv, v, nullptr, nullptr, 0);

  attn_qk<<<dim3(16, 16, 16), 256, 0, stream>>>(qh, ql, kh, kl, a1, a2, a3);

  softmax_colsum<<<dim3(64, 16), 256, 0, stream>>>(a1, partials);

  reduce_partials<<<dim3(8, 16), 256, 0, stream>>>(partials, csum);

  final_out<<<dim3(2048), 256, 0, stream>>>(v, csum, out);
}

// Round 5
// 249.509 us; speedup vs baseline: 2.0321x; 1.1300x over previous
//
#include <hip/hip_runtime.h>

// ---------------------------------------------------------------------------
// TrendAttentionLayer, round 5.
// R2-R4 algebra kept: only attn1 computed (attn2/attn3 are row subsets of it,
// fanned out at store time); single weighted colsum (w=1+[l%2==0]+[l%3==0]).
// R5 structural change: softmax+colsum FUSED into the attention kernel.
// A block owns 16 q-rows x all 2048 s-cols (4 waves x 512 cols, 128 acc
// VGPR/lane). Raw scores stored (compulsory output), then softmax runs
// entirely in registers (row max/sum via shfl + tiny LDS) -> the former
// 268 MB HBM re-read is eliminated. Partials (16 MB) -> small reduce.
// Proj GEMMs: 64x64 tiles (512 blocks) to fill all 256 CUs.
// ---------------------------------------------------------------------------

typedef short s16x8 __attribute__((ext_vector_type(8)));
typedef float f32x4 __attribute__((ext_vector_type(4)));
typedef unsigned short u16;

#define MFMA16(a, b, c) __builtin_amdgcn_mfma_f32_16x16x32_bf16((a), (b), (c), 0, 0, 0)

__device__ __forceinline__ u16 f32_to_bf16(float f) {
  unsigned u = __builtin_bit_cast(unsigned, f);
  unsigned r = u + 0x7fffu + ((u >> 16) & 1u);  // RTNE
  return (u16)(r >> 16);
}
__device__ __forceinline__ void split1(float x, u16& h, u16& l) {
  h = f32_to_bf16(x);
  l = f32_to_bf16(x - __builtin_bit_cast(float, (unsigned)h << 16));
}

// ---------------------------------------------------------------------------
// Kernel A: split X (4096x512 f32 row-major) into A-frag-major hi/lo planes:
// element (row = mt*16+lr, k = kc*32+g*8+j) -> [((mt*16+kc)*64 + g*16+lr)*8+j]
// ---------------------------------------------------------------------------
__global__ __launch_bounds__(256) void split_x(const float* __restrict__ X,
                                               u16* __restrict__ Xh,
                                               u16* __restrict__ Xl) {
  int t = blockIdx.x * 256 + threadIdx.x;  // < 262144
  int lane = t & 63;
  int kc = (t >> 6) & 15;
  int mt = t >> 10;
  int lr = lane & 15, g = lane >> 4;
  const float* p = X + (size_t)(mt * 16 + lr) * 512 + kc * 32 + g * 8;
  float4 a = *(const float4*)p;
  float4 b = *(const float4*)(p + 4);
  float x[8] = {a.x, a.y, a.z, a.w, b.x, b.y, b.z, b.w};
  s16x8 hv, lv;
#pragma unroll
  for (int j = 0; j < 8; ++j) {
    u16 hh, ll;
    split1(x[j], hh, ll);
    hv[j] = (short)hh;
    lv[j] = (short)ll;
  }
  size_t off = (size_t)t * 8;
  *(s16x8*)(Xh + off) = hv;
  *(s16x8*)(Xl + off) = lv;
}

// ---------------------------------------------------------------------------
// Kernel B: W (512x512 f32 [k][n]) -> B-frag-major hi/lo planes.
// ---------------------------------------------------------------------------
__global__ __launch_bounds__(256) void split_w(const float* __restrict__ W,
                                               u16* __restrict__ Wh,
                                               u16* __restrict__ Wl) {
  int t = blockIdx.x * 256 + threadIdx.x;  // < 32768
  int lane = t & 63;
  int kc = (t >> 6) & 15;
  int nt = t >> 10;
  int lr = lane & 15, g = lane >> 4;
  s16x8 hv, lv;
#pragma unroll
  for (int j = 0; j < 8; ++j) {
    float x = W[(size_t)(kc * 32 + g * 8 + j) * 512 + nt * 16 + lr];
    u16 hh, ll;
    split1(x, hh, ll);
    hv[j] = (short)hh;
    lv[j] = (short)ll;
  }
  size_t off = (size_t)t * 8;
  *(s16x8*)(Wh + off) = hv;
  *(s16x8*)(Wl + off) = lv;
}

// ---------------------------------------------------------------------------
// Kernel 1: projection GEMM Y = X @ W + b, 64x64 block tile (512 blocks ->
// all CUs busy), 4 waves 2x2 each 32x32, pure loads+MFMA K-loop.
// mode 0: f32 out (v). mode 1: attention frag-major hi/lo out (q,k).
// ---------------------------------------------------------------------------
__global__ __launch_bounds__(256) void proj_gemm(const u16* __restrict__ Xh,
                                                 const u16* __restrict__ Xl,
                                                 const u16* __restrict__ Wh,
                                                 const u16* __restrict__ Wl,
                                                 const float* __restrict__ bias,
                                                 float* __restrict__ Yf32,
                                                 u16* __restrict__ Yhi,
                                                 u16* __restrict__ Ylo,
                                                 int bf16mode) {
  int tid = threadIdx.x;
  int wid = tid >> 6, lane = tid & 63;
  int wr = wid >> 1, wc = wid & 1;
  int mtb = blockIdx.y * 4 + wr * 2;  // 16-row tile base (A), 0..255
  int ntb = blockIdx.x * 4 + wc * 2;  // 16-col tile base (B), 0..31

  f32x4 zero = {0.f, 0.f, 0.f, 0.f};
  f32x4 acc[2][2];
#pragma unroll
  for (int m = 0; m < 2; ++m)
#pragma unroll
    for (int n = 0; n < 2; ++n) acc[m][n] = zero;

  for (int kc = 0; kc < 16; ++kc) {
    s16x8 ah[2], al[2], bh[2], bl[2];
#pragma unroll
    for (int m = 0; m < 2; ++m) {
      size_t off = ((size_t)((mtb + m) * 16 + kc) * 64 + lane) * 8;
      ah[m] = *(const s16x8*)(Xh + off);
      al[m] = *(const s16x8*)(Xl + off);
    }
#pragma unroll
    for (int n = 0; n < 2; ++n) {
      size_t off = ((size_t)((ntb + n) * 16 + kc) * 64 + lane) * 8;
      bh[n] = *(const s16x8*)(Wh + off);
      bl[n] = *(const s16x8*)(Wl + off);
    }
#pragma unroll
    for (int m = 0; m < 2; ++m)
#pragma unroll
      for (int n = 0; n < 2; ++n) {
        acc[m][n] = MFMA16(ah[m], bh[n], acc[m][n]);
        acc[m][n] = MFMA16(ah[m], bl[n], acc[m][n]);
        acc[m][n] = MFMA16(al[m], bh[n], acc[m][n]);
      }
  }
  int cn = lane & 15, cr0 = (lane >> 4) * 4;
#pragma unroll
  for (int n = 0; n < 2; ++n) {
    int col = (ntb + n) * 16 + cn;
    float bv = bias[col];
#pragma unroll
    for (int m = 0; m < 2; ++m)
#pragma unroll
      for (int r = 0; r < 4; ++r) {
        int row = (mtb + m) * 16 + cr0 + r;
        float y = acc[m][n][r] + bv;
        if (!bf16mode) {
          Yf32[(size_t)row * 512 + col] = y;
        } else {
          int b = row >> 11, l = row & 2047;
          int h = col >> 6, e = col & 63;
          int bh2 = b * 8 + h;
          int lt = l >> 4, lr2 = l & 15;
          int kc2 = e >> 5, g2 = (e >> 3) & 3, j2 = e & 7;
          size_t idx = ((((size_t)bh2 * 128 + lt) * 2 + kc2) * 64 + g2 * 16 + lr2) * 8 + j2;
          u16 hh, ll;
          split1(y, hh, ll);
          Yhi[idx] = hh;
          Ylo[idx] = ll;
        }
      }
  }
}

// ---------------------------------------------------------------------------
// Kernel 2: FUSED attn + softmax + colsum.
// Block: 16 q-rows x 2048 s-cols of one bh; 4 waves, wave w covers cols
// [w*512, w*512+512) -> acc[32] f32x4 per lane (128 VGPR). Raw scores stored
// to a1 (+ a2/a3 row fanout), then softmax entirely in registers:
//   row max: reg-reduce + shfl_xor(1,2,4,8) + LDS across 4 waves
//   exp in place, row sum same way, weighted colsum via shfl_xor(16,32)+LDS.
// ---------------------------------------------------------------------------
__global__ __launch_bounds__(256, 2) void attn_fused(const u16* __restrict__ qh,
                                                     const u16* __restrict__ ql,
                                                     const u16* __restrict__ kh,
                                                     const u16* __restrict__ kl,
                                                     float* __restrict__ a1,
                                                     float* __restrict__ a2,
                                                     float* __restrict__ a3,
                                                     float* __restrict__ partials) {
  int bh = blockIdx.y;    // 0..15
  int lblk = blockIdx.x;  // 0..127 (16 rows each)
  int tid = threadIdx.x, wid = tid >> 6, lane = tid & 63;
  int wcol = wid;  // 0..3

  // A fragments (16 q rows), reused across all 32 col tiles.
  s16x8 qhf[2], qlf[2];
#pragma unroll
  for (int kc = 0; kc < 2; ++kc) {
    size_t off = ((((size_t)bh * 128 + lblk) * 2 + kc) * 64 + lane) * 8;
    qhf[kc] = *(const s16x8*)(qh + off);
    qlf[kc] = *(const s16x8*)(ql + off);
  }

  f32x4 acc[32];
#pragma unroll
  for (int t = 0; t < 32; ++t) acc[t] = (f32x4){0.f, 0.f, 0.f, 0.f};

#pragma unroll
  for (int t = 0; t < 32; ++t) {
    int st = wcol * 32 + t;
#pragma unroll
    for (int kc = 0; kc < 2; ++kc) {
      size_t off = ((((size_t)bh * 128 + st) * 2 + kc) * 64 + lane) * 8;
      s16x8 khf = *(const s16x8*)(kh + off);
      s16x8 klf = *(const s16x8*)(kl + off);
      acc[t] = MFMA16(qhf[kc], khf, acc[t]);
      acc[t] = MFMA16(qhf[kc], klf, acc[t]);
      acc[t] = MFMA16(qlf[kc], khf, acc[t]);
    }
  }

  // ---- store raw scores (D layout: col = lane&15, row = (lane>>4)*4 + r) --
  int cn = lane & 15, rg = lane >> 4;
  int lbase = lblk * 16;
  float* A1 = a1 + (size_t)bh * 2048 * 2048;
  float* A2 = a2 + (size_t)bh * 1024 * 2048;
  float* A3 = a3 + (size_t)bh * 683 * 2048;
#pragma unroll
  for (int r = 0; r < 4; ++r) {
    int l = lbase + rg * 4 + r;
    float* p1 = A1 + (size_t)l * 2048 + wcol * 512 + cn;
#pragma unroll
    for (int t = 0; t < 32; ++t) p1[t * 16] = acc[t][r];
    if ((l & 1) == 0) {
      float* p2 = A2 + (size_t)(l >> 1) * 2048 + wcol * 512 + cn;
#pragma unroll
      for (int t = 0; t < 32; ++t) __builtin_nontemporal_store(acc[t][r], p2 + t * 16);
    }
    if (l % 3 == 0) {
      float* p3 = A3 + (size_t)(l / 3) * 2048 + wcol * 512 + cn;
#pragma unroll
      for (int t = 0; t < 32; ++t) __builtin_nontemporal_store(acc[t][r], p3 + t * 16);
    }
  }

  // ---- row max (this wave's 512 cols, then across 4 waves via LDS) --------
  __shared__ float lred[16][4];
  float mrow[4];
#pragma unroll
  for (int r = 0; r < 4; ++r) {
    float m = acc[0][r];
#pragma unroll
    for (int t = 1; t < 32; ++t) m = fmaxf(m, acc[t][r]);
#pragma unroll
    for (int o = 1; o < 16; o <<= 1) m = fmaxf(m, __shfl_xor(m, o));
    mrow[r] = m;
  }
  if (cn == 0) {
#pragma unroll
    for (int r = 0; r < 4; ++r) lred[rg * 4 + r][wcol] = mrow[r];
  }
  __syncthreads();
  float mfin[4];
#pragma unroll
  for (int r = 0; r < 4; ++r) {
    int rr = rg * 4 + r;
    mfin[r] = fmaxf(fmaxf(lred[rr][0], lred[rr][1]), fmaxf(lred[rr][2], lred[rr][3]));
  }
  __syncthreads();  // lred reused for sums

  // ---- exp in place + row sums --------------------------------------------
  float zrow[4] = {0.f, 0.f, 0.f, 0.f};
#pragma unroll
  for (int t = 0; t < 32; ++t) {
#pragma unroll
    for (int r = 0; r < 4; ++r) {
      float p = __expf(acc[t][r] - mfin[r]);
      acc[t][r] = p;
      zrow[r] += p;
    }
  }
#pragma unroll
  for (int r = 0; r < 4; ++r) {
#pragma unroll
    for (int o = 1; o < 16; o <<= 1) zrow[r] += __shfl_xor(zrow[r], o);
  }
  if (cn == 0) {
#pragma unroll
    for (int r = 0; r < 4; ++r) lred[rg * 4 + r][wcol] = zrow[r];
  }
  __syncthreads();
  float winv[4];
#pragma unroll
  for (int r = 0; r < 4; ++r) {
    int rr = rg * 4 + r;
    int l = lbase + rr;
    float z = lred[rr][0] + lred[rr][1] + lred[rr][2] + lred[rr][3];
    float w = 1.f + (((l & 1) == 0) ? 1.f : 0.f) + ((l % 3 == 0) ? 1.f : 0.f);
    winv[r] = w / z;
  }

  // ---- weighted colsum -----------------------------------------------------
  __shared__ float pcol[2048];
#pragma unroll
  for (int t = 0; t < 32; ++t) {
    float cs = acc[t][0] * winv[0] + acc[t][1] * winv[1] + acc[t][2] * winv[2] +
               acc[t][3] * winv[3];
    cs += __shfl_xor(cs, 16);
    cs += __shfl_xor(cs, 32);
    if (lane < 16) pcol[wcol * 512 + t * 16 + cn] = cs;
  }
  __syncthreads();
  size_t pb = ((size_t)bh * 128 + lblk) * 2048;
#pragma unroll
  for (int i = 0; i < 8; ++i) partials[pb + i * 256 + tid] = pcol[i * 256 + tid];
}

// ---------------------------------------------------------------------------
// Kernel 3: csum_total[bh,s] = sum over 128 row-block partials.
// ---------------------------------------------------------------------------
__global__ __launch_bounds__(256) void reduce_partials(const float* __restrict__ partials,
                                                       float* __restrict__ csum) {
  int s = blockIdx.x * 256 + threadIdx.x;
  int bh = blockIdx.y;
  float acc = 0.f;
  for (int j = 0; j < 128; ++j) acc += partials[((size_t)(bh * 128 + j)) * 2048 + s];
  csum[(size_t)bh * 2048 + s] = acc;
}

// ---------------------------------------------------------------------------
// Kernel 4: out[b,s,h*64+e] = v[b,s,h,e] * csum_total[b,h,s] / 3
// ---------------------------------------------------------------------------
__global__ __launch_bounds__(256) void final_out(const float* __restrict__ v,
                                                 const float* __restrict__ csum,
                                                 float* __restrict__ out) {
  int idx = blockIdx.x * 256 + threadIdx.x;  // float4 index
  int h = (idx >> 4) & 7;
  int s = (idx >> 7) & 2047;
  int b = idx >> 18;
  float4 vv = ((const float4*)v)[idx];
  float c = csum[(size_t)(b * 8 + h) * 2048 + s] * (1.f / 3.f);
  float4 o = {vv.x * c, vv.y * c, vv.z * c, vv.w * c};
  ((float4*)out)[idx] = o;
}

// ---------------------------------------------------------------------------
extern "C" void kernel_launch(void* const* d_in, const int* in_sizes, int n_in,
                              void* d_out, int out_size, void* d_ws, size_t ws_size,
                              hipStream_t stream) {
  const float* queries = (const float*)d_in[0];
  const float* keys    = (const float*)d_in[1];
  const float* values  = (const float*)d_in[2];
  const float* Wq = (const float*)d_in[3];
  const float* bq = (const float*)d_in[4];
  const float* Wk = (const float*)d_in[5];
  const float* bk = (const float*)d_in[6];
  const float* Wv = (const float*)d_in[7];
  const float* bv = (const float*)d_in[8];

  float* out = (float*)d_out;   // (2,2048,512)    = 2097152
  float* a1 = out + 2097152;    // (2,8,2048,2048) = 67108864
  float* a2 = a1 + 67108864;    // (2,8,1024,2048) = 33554432
  float* a3 = a2 + 33554432;    // (2,8, 683,2048) = 22380544

  float* ws = (float*)d_ws;
  float* v = ws;                  // 2,097,152 f32 (8MB)
  u16* qh = (u16*)(v + 2097152);  // 4MB each
  u16* ql = qh + 2097152;
  u16* kh = ql + 2097152;
  u16* kl = kh + 2097152;
  u16* Wh = kl + 2097152;  // 0.5MB each
  u16* Wl = Wh + 262144;
  u16* Xh = Wl + 262144;  // 4MB each
  u16* Xl = Xh + 2097152;
  // partials (16 MB) alias Wh..Xl (9 MB, dead after projs) + 7 MB beyond.
  float* partials = (float*)Wh;                    // 16*128*2048 f32
  float* csum = partials + 16 * 128 * 2048;        // 32768 f32
  // (csum region lies past Xl; total ws use ~40.1 MB)

  // -- prep + projections (Wh/Wl, Xh/Xl reused serially, stream-ordered) ----
  split_w<<<dim3(128), 256, 0, stream>>>(Wq, Wh, Wl);
  split_x<<<dim3(1024), 256, 0, stream>>>(queries, Xh, Xl);
  proj_gemm<<<dim3(8, 64), 256, 0, stream>>>(Xh, Xl, Wh, Wl, bq, nullptr, qh, ql, 1);

  split_w<<<dim3(128), 256, 0, stream>>>(Wk, Wh, Wl);
  split_x<<<dim3(1024), 256, 0, stream>>>(keys, Xh, Xl);
  proj_gemm<<<dim3(8, 64), 256, 0, stream>>>(Xh, Xl, Wh, Wl, bk, nullptr, kh, kl, 1);

  split_w<<<dim3(128), 256, 0, stream>>>(Wv, Wh, Wl);
  split_x<<<dim3(1024), 256, 0, stream>>>(values, Xh, Xl);
  proj_gemm<<<dim3(8, 64), 256, 0, stream>>>(Xh, Xl, Wh, Wl, bv, v, nullptr, nullptr, 0);

  // -- fused attention + softmax + colsum ------------------------------------
  attn_fused<<<dim3(128, 16), 256, 0, stream>>>(qh, ql, kh, kl, a1, a2, a3, partials);

  reduce_partials<<<dim3(8, 16), 256, 0, stream>>>(partials, csum);

  final_out<<<dim3(2048), 256, 0, stream>>>(v, csum, out);
}

// Round 6
// 195.153 us; speedup vs baseline: 2.5981x; 1.2785x over previous
//
#include <hip/hip_runtime.h>

// ---------------------------------------------------------------------------
// TrendAttentionLayer, round 6.
// Algebra (R2-R5): only attn1 computed; attn2/attn3 = row subsets, fanned out
// at store time; single weighted in-register softmax/colsum
// (w = 1 + [l%2==0] + [l%3==0]); no attn re-read.
// R6 changes:
//  * attn_fused: 512-thread blocks, 8 waves x 256 cols, acc[16] (64 VGPR) ->
//    __launch_bounds__(512,4) caps VGPR at 128 -> 4 waves/SIMD (2x R5).
//  * ALL attn outputs NT-stored (a1 never re-read; L2 kept for k panels).
//  * Launch fusion: 1 split_all + 1 proj_gemm3 (z=3) -> 5 launches total.
// ---------------------------------------------------------------------------

typedef short s16x8 __attribute__((ext_vector_type(8)));
typedef float f32x4 __attribute__((ext_vector_type(4)));
typedef unsigned short u16;

#define MFMA16(a, b, c) __builtin_amdgcn_mfma_f32_16x16x32_bf16((a), (b), (c), 0, 0, 0)

__device__ __forceinline__ u16 f32_to_bf16(float f) {
  unsigned u = __builtin_bit_cast(unsigned, f);
  unsigned r = u + 0x7fffu + ((u >> 16) & 1u);  // RTNE
  return (u16)(r >> 16);
}
__device__ __forceinline__ void split1(float x, u16& h, u16& l) {
  h = f32_to_bf16(x);
  l = f32_to_bf16(x - __builtin_bit_cast(float, (unsigned)h << 16));
}

// ---------------------------------------------------------------------------
// Kernel A: split ALL inputs into frag-major hi/lo planes in one launch.
// grid (1152, 3): y selects matrix (q/k/v); x<1024 -> X planes, x>=1024 -> W.
// X: element (row = mt*16+lr, k = kc*32+g*8+j) -> [((mt*16+kc)*64+g*16+lr)*8+j]
// W: element (n  = nt*16+lr, k = kc*32+g*8+j) -> same frag-major form (B-op).
// ---------------------------------------------------------------------------
__global__ __launch_bounds__(256) void split_all(const float* __restrict__ in_q,
                                                 const float* __restrict__ in_k,
                                                 const float* __restrict__ in_v,
                                                 const float* __restrict__ Wq,
                                                 const float* __restrict__ Wk,
                                                 const float* __restrict__ Wv,
                                                 u16* __restrict__ Xsplit,
                                                 u16* __restrict__ Wsplit) {
  int which = blockIdx.y;  // 0,1,2
  int bx = blockIdx.x;
  if (bx < 1024) {
    const float* X = (which == 0) ? in_q : (which == 1) ? in_k : in_v;
    u16* Xh = Xsplit + (size_t)which * 2 * 2097152;
    u16* Xl = Xh + 2097152;
    int t = bx * 256 + threadIdx.x;  // < 262144
    int lane = t & 63;
    int kc = (t >> 6) & 15;
    int mt = t >> 10;
    int lr = lane & 15, g = lane >> 4;
    const float* p = X + (size_t)(mt * 16 + lr) * 512 + kc * 32 + g * 8;
    float4 a = *(const float4*)p;
    float4 b = *(const float4*)(p + 4);
    float x[8] = {a.x, a.y, a.z, a.w, b.x, b.y, b.z, b.w};
    s16x8 hv, lv;
#pragma unroll
    for (int j = 0; j < 8; ++j) {
      u16 hh, ll;
      split1(x[j], hh, ll);
      hv[j] = (short)hh;
      lv[j] = (short)ll;
    }
    size_t off = (size_t)t * 8;
    *(s16x8*)(Xh + off) = hv;
    *(s16x8*)(Xl + off) = lv;
  } else {
    const float* W = (which == 0) ? Wq : (which == 1) ? Wk : Wv;
    u16* Wh = Wsplit + (size_t)which * 2 * 262144;
    u16* Wl = Wh + 262144;
    int t = (bx - 1024) * 256 + threadIdx.x;  // < 32768
    int lane = t & 63;
    int kc = (t >> 6) & 15;
    int nt = t >> 10;
    int lr = lane & 15, g = lane >> 4;
    s16x8 hv, lv;
#pragma unroll
    for (int j = 0; j < 8; ++j) {
      float x = W[(size_t)(kc * 32 + g * 8 + j) * 512 + nt * 16 + lr];
      u16 hh, ll;
      split1(x, hh, ll);
      hv[j] = (short)hh;
      lv[j] = (short)ll;
    }
    size_t off = (size_t)t * 8;
    *(s16x8*)(Wh + off) = hv;
    *(s16x8*)(Wl + off) = lv;
  }
}

// ---------------------------------------------------------------------------
// Kernel 1: all three projection GEMMs in one launch (blockIdx.z selects).
// 64x64 block tile, 4 waves 2x2 each 32x32, pure loads+MFMA K-loop.
// z=0 -> q (frag-major bf16 out), z=1 -> k (same), z=2 -> v (f32 out).
// ---------------------------------------------------------------------------
__global__ __launch_bounds__(256) void proj_gemm3(const u16* __restrict__ Xsplit,
                                                  const u16* __restrict__ Wsplit,
                                                  const float* __restrict__ bq,
                                                  const float* __restrict__ bk,
                                                  const float* __restrict__ bv,
                                                  float* __restrict__ vout,
                                                  u16* __restrict__ qh,
                                                  u16* __restrict__ ql,
                                                  u16* __restrict__ kh,
                                                  u16* __restrict__ kl) {
  int z = blockIdx.z;
  const u16* Xh = Xsplit + (size_t)z * 2 * 2097152;
  const u16* Xl = Xh + 2097152;
  const u16* Wh = Wsplit + (size_t)z * 2 * 262144;
  const u16* Wl = Wh + 262144;
  const float* bias = (z == 0) ? bq : (z == 1) ? bk : bv;
  u16* Yhi = (z == 0) ? qh : kh;
  u16* Ylo = (z == 0) ? ql : kl;

  int tid = threadIdx.x;
  int wid = tid >> 6, lane = tid & 63;
  int wr = wid >> 1, wc = wid & 1;
  int mtb = blockIdx.y * 4 + wr * 2;  // 16-row tile base, 0..255
  int ntb = blockIdx.x * 4 + wc * 2;  // 16-col tile base, 0..31

  f32x4 zero = {0.f, 0.f, 0.f, 0.f};
  f32x4 acc[2][2];
#pragma unroll
  for (int m = 0; m < 2; ++m)
#pragma unroll
    for (int n = 0; n < 2; ++n) acc[m][n] = zero;

  for (int kc = 0; kc < 16; ++kc) {
    s16x8 ah[2], al[2], bh[2], bl[2];
#pragma unroll
    for (int m = 0; m < 2; ++m) {
      size_t off = ((size_t)((mtb + m) * 16 + kc) * 64 + lane) * 8;
      ah[m] = *(const s16x8*)(Xh + off);
      al[m] = *(const s16x8*)(Xl + off);
    }
#pragma unroll
    for (int n = 0; n < 2; ++n) {
      size_t off = ((size_t)((ntb + n) * 16 + kc) * 64 + lane) * 8;
      bh[n] = *(const s16x8*)(Wh + off);
      bl[n] = *(const s16x8*)(Wl + off);
    }
#pragma unroll
    for (int m = 0; m < 2; ++m)
#pragma unroll
      for (int n = 0; n < 2; ++n) {
        acc[m][n] = MFMA16(ah[m], bh[n], acc[m][n]);
        acc[m][n] = MFMA16(ah[m], bl[n], acc[m][n]);
        acc[m][n] = MFMA16(al[m], bh[n], acc[m][n]);
      }
  }
  int cn = lane & 15, cr0 = (lane >> 4) * 4;
#pragma unroll
  for (int n = 0; n < 2; ++n) {
    int col = (ntb + n) * 16 + cn;
    float bv_ = bias[col];
#pragma unroll
    for (int m = 0; m < 2; ++m)
#pragma unroll
      for (int r = 0; r < 4; ++r) {
        int row = (mtb + m) * 16 + cr0 + r;
        float y = acc[m][n][r] + bv_;
        if (z == 2) {
          vout[(size_t)row * 512 + col] = y;
        } else {
          int b = row >> 11, l = row & 2047;
          int h = col >> 6, e = col & 63;
          int bh2 = b * 8 + h;
          int lt = l >> 4, lr2 = l & 15;
          int kc2 = e >> 5, g2 = (e >> 3) & 3, j2 = e & 7;
          size_t idx = ((((size_t)bh2 * 128 + lt) * 2 + kc2) * 64 + g2 * 16 + lr2) * 8 + j2;
          u16 hh, ll;
          split1(y, hh, ll);
          Yhi[idx] = hh;
          Ylo[idx] = ll;
        }
      }
  }
}

// ---------------------------------------------------------------------------
// Kernel 2: FUSED attn + softmax + colsum. Block = 16 q-rows x 2048 s-cols,
// 512 threads: wave w covers cols [w*256, w*256+256) -> acc[16] (64 VGPR).
// All score stores NT (never re-read). Softmax in registers:
//   row max/sum: reg-reduce + shfl_xor(1,2,4,8) + LDS across 8 waves;
//   weighted colsum via shfl_xor(16,32) + LDS -> per-block partials.
// ---------------------------------------------------------------------------
__global__ __launch_bounds__(512, 4) void attn_fused(const u16* __restrict__ qh,
                                                     const u16* __restrict__ ql,
                                                     const u16* __restrict__ kh,
                                                     const u16* __restrict__ kl,
                                                     float* __restrict__ a1,
                                                     float* __restrict__ a2,
                                                     float* __restrict__ a3,
                                                     float* __restrict__ partials) {
  int bh = blockIdx.y;    // 0..15
  int lblk = blockIdx.x;  // 0..127
  int tid = threadIdx.x, wid = tid >> 6, lane = tid & 63;

  // A fragments (block's 16 q rows) — identical for every wave.
  s16x8 qhf[2], qlf[2];
#pragma unroll
  for (int kc = 0; kc < 2; ++kc) {
    size_t off = ((((size_t)bh * 128 + lblk) * 2 + kc) * 64 + lane) * 8;
    qhf[kc] = *(const s16x8*)(qh + off);
    qlf[kc] = *(const s16x8*)(ql + off);
  }

  f32x4 acc[16];
#pragma unroll
  for (int t = 0; t < 16; ++t) acc[t] = (f32x4){0.f, 0.f, 0.f, 0.f};

#pragma unroll
  for (int t = 0; t < 16; ++t) {
    int st = wid * 16 + t;
#pragma unroll
    for (int kc = 0; kc < 2; ++kc) {
      size_t off = ((((size_t)bh * 128 + st) * 2 + kc) * 64 + lane) * 8;
      s16x8 khf = *(const s16x8*)(kh + off);
      s16x8 klf = *(const s16x8*)(kl + off);
      acc[t] = MFMA16(qhf[kc], khf, acc[t]);
      acc[t] = MFMA16(qhf[kc], klf, acc[t]);
      acc[t] = MFMA16(qlf[kc], khf, acc[t]);
    }
  }

  // ---- NT-store raw scores (D layout: col = lane&15, row = (lane>>4)*4+r) -
  int cn = lane & 15, rg = lane >> 4;
  int lbase = lblk * 16;
  float* A1 = a1 + (size_t)bh * 2048 * 2048;
  float* A2 = a2 + (size_t)bh * 1024 * 2048;
  float* A3 = a3 + (size_t)bh * 683 * 2048;
#pragma unroll
  for (int r = 0; r < 4; ++r) {
    int l = lbase + rg * 4 + r;
    float* p1 = A1 + (size_t)l * 2048 + wid * 256 + cn;
#pragma unroll
    for (int t = 0; t < 16; ++t) __builtin_nontemporal_store(acc[t][r], p1 + t * 16);
    if ((l & 1) == 0) {
      float* p2 = A2 + (size_t)(l >> 1) * 2048 + wid * 256 + cn;
#pragma unroll
      for (int t = 0; t < 16; ++t) __builtin_nontemporal_store(acc[t][r], p2 + t * 16);
    }
    if (l % 3 == 0) {
      float* p3 = A3 + (size_t)(l / 3) * 2048 + wid * 256 + cn;
#pragma unroll
      for (int t = 0; t < 16; ++t) __builtin_nontemporal_store(acc[t][r], p3 + t * 16);
    }
  }

  // ---- row max (wave's 256 cols -> across 8 waves via LDS) ----------------
  __shared__ float lred[16][8];
  float mrow[4];
#pragma unroll
  for (int r = 0; r < 4; ++r) {
    float m = acc[0][r];
#pragma unroll
    for (int t = 1; t < 16; ++t) m = fmaxf(m, acc[t][r]);
#pragma unroll
    for (int o = 1; o < 16; o <<= 1) m = fmaxf(m, __shfl_xor(m, o));
    mrow[r] = m;
  }
  if (cn == 0) {
#pragma unroll
    for (int r = 0; r < 4; ++r) lred[rg * 4 + r][wid] = mrow[r];
  }
  __syncthreads();
  float mfin[4];
#pragma unroll
  for (int r = 0; r < 4; ++r) {
    int rr = rg * 4 + r;
    float m = lred[rr][0];
#pragma unroll
    for (int w = 1; w < 8; ++w) m = fmaxf(m, lred[rr][w]);
    mfin[r] = m;
  }
  __syncthreads();  // lred reused for sums

  // ---- exp in place + row sums --------------------------------------------
  float zrow[4] = {0.f, 0.f, 0.f, 0.f};
#pragma unroll
  for (int t = 0; t < 16; ++t) {
#pragma unroll
    for (int r = 0; r < 4; ++r) {
      float p = __expf(acc[t][r] - mfin[r]);
      acc[t][r] = p;
      zrow[r] += p;
    }
  }
#pragma unroll
  for (int r = 0; r < 4; ++r) {
#pragma unroll
    for (int o = 1; o < 16; o <<= 1) zrow[r] += __shfl_xor(zrow[r], o);
  }
  if (cn == 0) {
#pragma unroll
    for (int r = 0; r < 4; ++r) lred[rg * 4 + r][wid] = zrow[r];
  }
  __syncthreads();
  float winv[4];
#pragma unroll
  for (int r = 0; r < 4; ++r) {
    int rr = rg * 4 + r;
    int l = lbase + rr;
    float zs = lred[rr][0];
#pragma unroll
    for (int w = 1; w < 8; ++w) zs += lred[rr][w];
    float w_ = 1.f + (((l & 1) == 0) ? 1.f : 0.f) + ((l % 3 == 0) ? 1.f : 0.f);
    winv[r] = w_ / zs;
  }

  // ---- weighted colsum -----------------------------------------------------
  __shared__ float pcol[2048];
#pragma unroll
  for (int t = 0; t < 16; ++t) {
    float cs = acc[t][0] * winv[0] + acc[t][1] * winv[1] + acc[t][2] * winv[2] +
               acc[t][3] * winv[3];
    cs += __shfl_xor(cs, 16);
    cs += __shfl_xor(cs, 32);
    if (lane < 16) pcol[wid * 256 + t * 16 + cn] = cs;
  }
  __syncthreads();
  size_t pb = ((size_t)bh * 128 + lblk) * 2048;
#pragma unroll
  for (int i = 0; i < 4; ++i) partials[pb + i * 512 + tid] = pcol[i * 512 + tid];
}

// ---------------------------------------------------------------------------
// Kernel 3: csum_total[bh,s] = sum over 128 row-block partials.
// ---------------------------------------------------------------------------
__global__ __launch_bounds__(256) void reduce_partials(const float* __restrict__ partials,
                                                       float* __restrict__ csum) {
  int s = blockIdx.x * 256 + threadIdx.x;
  int bh = blockIdx.y;
  float acc = 0.f;
  for (int j = 0; j < 128; ++j) acc += partials[((size_t)(bh * 128 + j)) * 2048 + s];
  csum[(size_t)bh * 2048 + s] = acc;
}

// ---------------------------------------------------------------------------
// Kernel 4: out[b,s,h*64+e] = v[b,s,h,e] * csum_total[b,h,s] / 3
// ---------------------------------------------------------------------------
__global__ __launch_bounds__(256) void final_out(const float* __restrict__ v,
                                                 const float* __restrict__ csum,
                                                 float* __restrict__ out) {
  int idx = blockIdx.x * 256 + threadIdx.x;  // float4 index
  int h = (idx >> 4) & 7;
  int s = (idx >> 7) & 2047;
  int b = idx >> 18;
  float4 vv = ((const float4*)v)[idx];
  float c = csum[(size_t)(b * 8 + h) * 2048 + s] * (1.f / 3.f);
  float4 o = {vv.x * c, vv.y * c, vv.z * c, vv.w * c};
  ((float4*)out)[idx] = o;
}

// ---------------------------------------------------------------------------
extern "C" void kernel_launch(void* const* d_in, const int* in_sizes, int n_in,
                              void* d_out, int out_size, void* d_ws, size_t ws_size,
                              hipStream_t stream) {
  const float* queries = (const float*)d_in[0];
  const float* keys    = (const float*)d_in[1];
  const float* values  = (const float*)d_in[2];
  const float* Wq = (const float*)d_in[3];
  const float* bq = (const float*)d_in[4];
  const float* Wk = (const float*)d_in[5];
  const float* bk = (const float*)d_in[6];
  const float* Wv = (const float*)d_in[7];
  const float* bv = (const float*)d_in[8];

  float* out = (float*)d_out;   // (2,2048,512)    = 2097152
  float* a1 = out + 2097152;    // (2,8,2048,2048) = 67108864
  float* a2 = a1 + 67108864;    // (2,8,1024,2048) = 33554432
  float* a3 = a2 + 33554432;    // (2,8, 683,2048) = 22380544

  float* ws = (float*)d_ws;
  float* v = ws;                        // 8 MB
  u16* qh = (u16*)(v + 2097152);        // 4 MB each
  u16* ql = qh + 2097152;
  u16* kh = ql + 2097152;
  u16* kl = kh + 2097152;
  u16* Wsplit = kl + 2097152;           // 6 x 262144 u16 = 3 MB
  u16* Xsplit = Wsplit + 6 * 262144;    // 6 x 2097152 u16 = 24 MB
  // aliases (dead after proj_gemm3):
  float* partials = (float*)Xsplit;     // 16*128*2048 f32 = 16 MB (<= 24 MB)
  float* csum = (float*)Wsplit;         // 32768 f32 (<= 3 MB)

  split_all<<<dim3(1152, 3), 256, 0, stream>>>(queries, keys, values, Wq, Wk, Wv,
                                               Xsplit, Wsplit);

  proj_gemm3<<<dim3(8, 64, 3), 256, 0, stream>>>(Xsplit, Wsplit, bq, bk, bv, v,
                                                 qh, ql, kh, kl);

  attn_fused<<<dim3(128, 16), 512, 0, stream>>>(qh, ql, kh, kl, a1, a2, a3, partials);

  reduce_partials<<<dim3(8, 16), 256, 0, stream>>>(partials, csum);

  final_out<<<dim3(2048), 256, 0, stream>>>(v, csum, out);
}